// Round 1
// baseline (353.693 us; speedup 1.0000x reference)
//
#include <hip/hip_runtime.h>

#define NCH 12
#define NB  4
#define BC  48
#define HW0 (512 * 512)

// ---------------------------------------------------------------------------
// Gaussian 1-D weights (win=11, sigma=1.5), computed per-thread in registers.
__device__ __forceinline__ void make_gauss(float* gk) {
    float s = 0.f;
#pragma unroll
    for (int k = 0; k < 11; ++k) {
        float d = (float)(k - 5);
        float e = expf(-d * d / 4.5f);   // 2*sigma^2 = 4.5
        gk[k] = e; s += e;
    }
    float inv = 1.f / s;
#pragma unroll
    for (int k = 0; k < 11; ++k) gk[k] *= inv;
}

// ---------------------------------------------------------------------------
__global__ void k_init(double* acc) {
    int i = threadIdx.x;
    if (i < 480) acc[i] = 0.0;   // acc[scale][2][48]
}

// softmax over the 12 channels, one thread per (b,h,w)
__global__ void k_softmax(const float* __restrict__ pred, float* __restrict__ X0) {
    int i = blockIdx.x * blockDim.x + threadIdx.x;
    if (i >= NB * HW0) return;
    int b = i >> 18;               // HW0 = 2^18
    int p = i & (HW0 - 1);
    const float* base = pred + (((size_t)b * NCH) << 18) + p;
    float v[NCH];
    float mx = -1e30f;
#pragma unroll
    for (int c = 0; c < NCH; ++c) { v[c] = base[(size_t)c << 18]; mx = fmaxf(mx, v[c]); }
    float s = 0.f;
#pragma unroll
    for (int c = 0; c < NCH; ++c) { v[c] = expf(v[c] - mx); s += v[c]; }
    float inv = 1.f / s;
    float* ob = X0 + (((size_t)b * NCH) << 18) + p;
#pragma unroll
    for (int c = 0; c < NCH; ++c) ob[(size_t)c << 18] = v[c] * inv;
}

// generic 2x2 avg pool on [BC, IH, IW] -> [BC, IH/2, IW/2]
__global__ void k_pool(const float* __restrict__ in, float* __restrict__ out,
                       int IH, int IW) {
    int OH = IH >> 1, OW = IW >> 1;
    int n = BC * OH * OW;
    int i = blockIdx.x * blockDim.x + threadIdx.x;
    if (i >= n) return;
    int ow = i % OW; int t = i / OW; int oh = t % OH; int bc = t / OH;
    const float* p = in + ((size_t)bc * IH + 2 * oh) * IW + 2 * ow;
    out[i] = 0.25f * (p[0] + p[1] + p[IW] + p[IW + 1]);
}

// Y1 (scale-1 pooled one-hot) directly from target: one thread per (b,h,w) of 256^2
__global__ void k_pool_y1(const int* __restrict__ tgt, float* __restrict__ Y1) {
    int i = blockIdx.x * blockDim.x + threadIdx.x;
    if (i >= NB * 256 * 256) return;
    int w = i & 255; int t = i >> 8; int h = t & 255; int b = t >> 8;
    const int* p = tgt + ((size_t)b * 512 + 2 * h) * 512 + 2 * w;
    int t0 = p[0], t1 = p[1], t2 = p[512], t3 = p[513];
#pragma unroll
    for (int c = 0; c < NCH; ++c) {
        float v = 0.25f * (float)((t0 == c) + (t1 == c) + (t2 == c) + (t3 == c));
        Y1[(((size_t)b * NCH + c) << 16) + (h << 8) + w] = v;
    }
}

// ---------------------------------------------------------------------------
// Fused SSIM-index per scale. One block = one 32x32 output tile of one (b,c)
// image. Separable 11-tap conv via LDS: load 42x42 halo, horizontal pass into
// 5 temp arrays [42][32], vertical pass -> per-pixel cs/ss -> block reduce ->
// one double atomicAdd per quantity.
template <bool ONE_HOT>
__global__ __launch_bounds__(256)
void k_ssim(const float* __restrict__ X, const float* __restrict__ Y,
            const int* __restrict__ tgt, int H, int W, int OH, int OW,
            int tilesX, double* __restrict__ acc, int scale) {
    __shared__ float sx[42 * 42];
    __shared__ float sy[42 * 42];
    __shared__ float tm[5][42 * 32];
    __shared__ float red[2][4];

    const int bc = blockIdx.y;
    const int tile = blockIdx.x;
    const int ty = tile / tilesX, tx = tile % tilesX;
    const int oy = ty * 32, ox = tx * 32;
    const int tid = threadIdx.x;

    float gk[11];
    make_gauss(gk);

    const float* Xb = X + (size_t)bc * H * W;
    const int b = bc / NCH, c = bc % NCH;
    const int* Tb = tgt + (size_t)b * H * W;            // used only if ONE_HOT
    const float* Yb = ONE_HOT ? (const float*)nullptr : Y + (size_t)bc * H * W;

    // ---- load halo tile (zero-pad out of range; those only feed invalid outputs)
    for (int i = tid; i < 42 * 42; i += 256) {
        int rr = i / 42, cc = i % 42;
        int gy = oy + rr, gx = ox + cc;
        bool ok = (gy < H) && (gx < W);
        float xv = ok ? Xb[(size_t)gy * W + gx] : 0.f;
        float yv;
        if (ONE_HOT) yv = (ok && Tb[(size_t)gy * W + gx] == c) ? 1.f : 0.f;
        else         yv = ok ? Yb[(size_t)gy * W + gx] : 0.f;
        sx[i] = xv; sy[i] = yv;
    }
    __syncthreads();

    // ---- horizontal conv: 42 rows x 32 cols -> 5 moment arrays
    for (int i = tid; i < 42 * 32; i += 256) {
        int rr = i >> 5, cc = i & 31;
        const float* px = sx + rr * 42 + cc;
        const float* py = sy + rr * 42 + cc;
        float ax = 0.f, ay = 0.f, axx = 0.f, ayy = 0.f, axy = 0.f;
#pragma unroll
        for (int k = 0; k < 11; ++k) {
            float g = gk[k], xv = px[k], yv = py[k];
            ax  += g * xv;      ay  += g * yv;
            axx += g * xv * xv; ayy += g * yv * yv; axy += g * xv * yv;
        }
        tm[0][i] = ax; tm[1][i] = ay; tm[2][i] = axx; tm[3][i] = ayy; tm[4][i] = axy;
    }
    __syncthreads();

    // ---- vertical conv + SSIM per pixel
    const float C1 = 1e-4f, C2 = 9e-4f;
    float cs_l = 0.f, ss_l = 0.f;
    for (int i = tid; i < 32 * 32; i += 256) {
        int r = i >> 5, cc = i & 31;
        if (oy + r < OH && ox + cc < OW) {
            float m1 = 0.f, m2 = 0.f, sxx = 0.f, syy = 0.f, sxy = 0.f;
#pragma unroll
            for (int k = 0; k < 11; ++k) {
                int idx = (r + k) * 32 + cc;
                float g = gk[k];
                m1  += g * tm[0][idx]; m2  += g * tm[1][idx];
                sxx += g * tm[2][idx]; syy += g * tm[3][idx]; sxy += g * tm[4][idx];
            }
            float m11 = m1 * m1, m22 = m2 * m2, m12 = m1 * m2;
            float v1 = sxx - m11, v2 = syy - m22, cov = sxy - m12;
            float cs = (2.f * cov + C2) / (v1 + v2 + C2);
            float ss = (2.f * m12 + C1) / (m11 + m22 + C1) * cs;
            cs_l += cs; ss_l += ss;
        }
    }

    // ---- block reduction (wave64 shuffle, then 4 wave partials)
    for (int off = 32; off; off >>= 1) {
        cs_l += __shfl_down(cs_l, off);
        ss_l += __shfl_down(ss_l, off);
    }
    int wv = tid >> 6, ln = tid & 63;
    if (ln == 0) { red[0][wv] = cs_l; red[1][wv] = ss_l; }
    __syncthreads();
    if (tid == 0) {
        double cs_b = (double)red[0][0] + (double)red[0][1] + (double)red[0][2] + (double)red[0][3];
        double ss_b = (double)red[1][0] + (double)red[1][1] + (double)red[1][2] + (double)red[1][3];
        atomicAdd(&acc[scale * 96 + bc], cs_b);
        atomicAdd(&acc[scale * 96 + 48 + bc], ss_b);
    }
}

// ---------------------------------------------------------------------------
__global__ void k_final(const double* __restrict__ acc, float* __restrict__ out) {
    const float wts[5] = {0.0448f, 0.2856f, 0.3001f, 0.2363f, 0.1333f};
    const float cnt[5] = {252004.f, 60516.f, 13924.f, 2916.f, 484.f}; // 502^2..22^2
    int tid = threadIdx.x;
    float msss = 0.f;
    if (tid < BC) {
        msss = 1.f;
#pragma unroll
        for (int s = 0; s < 5; ++s) {
            double a = (s < 4) ? acc[s * 96 + tid] : acc[s * 96 + 48 + tid];
            float v = fmaxf((float)(a / (double)cnt[s]), 0.f);
            msss *= powf(v, wts[s]);
        }
    }
    for (int off = 32; off; off >>= 1) msss += __shfl_down(msss, off);
    if (tid == 0) out[0] = 1.f - msss * (1.f / (float)BC);
}

// ---------------------------------------------------------------------------
extern "C" void kernel_launch(void* const* d_in, const int* in_sizes, int n_in,
                              void* d_out, int out_size, void* d_ws, size_t ws_size,
                              hipStream_t stream) {
    const float* pred = (const float*)d_in[0];
    const int*   tgt  = (const int*)d_in[1];
    float* out = (float*)d_out;

    // workspace layout
    double* acc = (double*)d_ws;                       // 480 doubles
    float* X0 = (float*)(acc + 480);                   // [48,512,512]
    float* X1 = X0 + (size_t)BC * 512 * 512;           // [48,256,256]
    float* X2 = X1 + (size_t)BC * 256 * 256;           // [48,128,128]
    float* X3 = X2 + (size_t)BC * 128 * 128;           // [48,64,64]
    float* X4 = X3 + (size_t)BC * 64 * 64;             // [48,32,32]
    float* Y1 = X4 + (size_t)BC * 32 * 32;             // [48,256,256]
    float* Y2 = Y1 + (size_t)BC * 256 * 256;
    float* Y3 = Y2 + (size_t)BC * 128 * 128;
    float* Y4 = Y3 + (size_t)BC * 64 * 64;

    k_init<<<1, 512, 0, stream>>>(acc);
    k_softmax<<<(NB * HW0 + 255) / 256, 256, 0, stream>>>(pred, X0);

    // scale 0: y = one-hot(target) on the fly
    k_ssim<true><<<dim3(16 * 16, BC), 256, 0, stream>>>(
        X0, (const float*)nullptr, tgt, 512, 512, 502, 502, 16, acc, 0);

    // pooled chains
    k_pool<<<(BC * 256 * 256 + 255) / 256, 256, 0, stream>>>(X0, X1, 512, 512);
    k_pool_y1<<<(NB * 256 * 256 + 255) / 256, 256, 0, stream>>>(tgt, Y1);

    k_ssim<false><<<dim3(8 * 8, BC), 256, 0, stream>>>(
        X1, Y1, tgt, 256, 256, 246, 246, 8, acc, 1);

    k_pool<<<(BC * 128 * 128 + 255) / 256, 256, 0, stream>>>(X1, X2, 256, 256);
    k_pool<<<(BC * 128 * 128 + 255) / 256, 256, 0, stream>>>(Y1, Y2, 256, 256);

    k_ssim<false><<<dim3(4 * 4, BC), 256, 0, stream>>>(
        X2, Y2, tgt, 128, 128, 118, 118, 4, acc, 2);

    k_pool<<<(BC * 64 * 64 + 255) / 256, 256, 0, stream>>>(X2, X3, 128, 128);
    k_pool<<<(BC * 64 * 64 + 255) / 256, 256, 0, stream>>>(Y2, Y3, 128, 128);

    k_ssim<false><<<dim3(2 * 2, BC), 256, 0, stream>>>(
        X3, Y3, tgt, 64, 64, 54, 54, 2, acc, 3);

    k_pool<<<(BC * 32 * 32 + 255) / 256, 256, 0, stream>>>(X3, X4, 64, 64);
    k_pool<<<(BC * 32 * 32 + 255) / 256, 256, 0, stream>>>(Y3, Y4, 64, 64);

    k_ssim<false><<<dim3(1, BC), 256, 0, stream>>>(
        X4, Y4, tgt, 32, 32, 22, 22, 1, acc, 4);

    k_final<<<1, 64, 0, stream>>>(acc, out);
}

// Round 2
// 320.599 us; speedup vs baseline: 1.1032x; 1.1032x over previous
//
#include <hip/hip_runtime.h>

#define NCH 12
#define NB  4
#define BC  48
#define HW0 (512 * 512)

// Gaussian 1-D weights (win=11, sigma=1.5), exact to f32 — computed offline.
// g[k] = exp(-(k-5)^2/4.5) / sum
#define GK_INIT { 0.00102840f, 0.00759863f, 0.03600078f, 0.10936081f, \
                  0.21300541f, 0.26601164f, 0.21300541f, 0.10936081f, \
                  0.03600078f, 0.00759863f, 0.00102840f }

// ---------------------------------------------------------------------------
__global__ void k_init(double* acc) {
    int i = threadIdx.x;
    if (i < 480) acc[i] = 0.0;   // acc[scale][2][48]
}

// softmax over the 12 channels, one thread per (b,h,w)
__global__ void k_softmax(const float* __restrict__ pred, float* __restrict__ X0) {
    int i = blockIdx.x * blockDim.x + threadIdx.x;
    if (i >= NB * HW0) return;
    int b = i >> 18;               // HW0 = 2^18
    int p = i & (HW0 - 1);
    const float* base = pred + (((size_t)b * NCH) << 18) + p;
    float v[NCH];
    float mx = -1e30f;
#pragma unroll
    for (int c = 0; c < NCH; ++c) { v[c] = base[(size_t)c << 18]; mx = fmaxf(mx, v[c]); }
    float s = 0.f;
#pragma unroll
    for (int c = 0; c < NCH; ++c) { v[c] = expf(v[c] - mx); s += v[c]; }
    float inv = 1.f / s;
    float* ob = X0 + (((size_t)b * NCH) << 18) + p;
#pragma unroll
    for (int c = 0; c < NCH; ++c) ob[(size_t)c << 18] = v[c] * inv;
}

// generic 2x2 avg pool on [BC, IH, IW] -> [BC, IH/2, IW/2]
__global__ void k_pool(const float* __restrict__ in, float* __restrict__ out,
                       int IH, int IW) {
    int OH = IH >> 1, OW = IW >> 1;
    int n = BC * OH * OW;
    int i = blockIdx.x * blockDim.x + threadIdx.x;
    if (i >= n) return;
    int ow = i % OW; int t = i / OW; int oh = t % OH; int bc = t / OH;
    const float* p = in + ((size_t)bc * IH + 2 * oh) * IW + 2 * ow;
    out[i] = 0.25f * (p[0] + p[1] + p[IW] + p[IW + 1]);
}

// Y1 (scale-1 pooled one-hot) directly from target
__global__ void k_pool_y1(const int* __restrict__ tgt, float* __restrict__ Y1) {
    int i = blockIdx.x * blockDim.x + threadIdx.x;
    if (i >= NB * 256 * 256) return;
    int w = i & 255; int t = i >> 8; int h = t & 255; int b = t >> 8;
    const int* p = tgt + ((size_t)b * 512 + 2 * h) * 512 + 2 * w;
    int t0 = p[0], t1 = p[1], t2 = p[512], t3 = p[513];
#pragma unroll
    for (int c = 0; c < NCH; ++c) {
        float v = 0.25f * (float)((t0 == c) + (t1 == c) + (t2 == c) + (t3 == c));
        Y1[(((size_t)b * NCH + c) << 16) + (h << 8) + w] = v;
    }
}

// ---------------------------------------------------------------------------
// Fused SSIM-index per scale. One block = one 32x32 output tile of one (b,c).
// Separable 11-tap conv via LDS with blocking:
//  - horizontal: each thread does a COLUMN-PAIR (12 contiguous floats via
//    float2 reads serve 2 outputs: 44 -> 12 LDS reads per output pair)
//  - vertical:   each thread does 4 consecutive output rows (14 streamed row
//    reads serve 4 outputs: 220 -> 56 reads), accumulators in registers
// Scale 0 (ONE_HOT): y is binary so conv(y^2)==conv(y) -> only 4 moment
// arrays, LDS 36.3 KB -> 4 blocks/CU. Generic: 5 arrays, 41.8 KB -> 3/CU.
// tm row stride = 33 (conflict-free scalar writes/reads).
template <bool ONE_HOT>
__global__ __launch_bounds__(256, 4)
void k_ssim(const float* __restrict__ X, const float* __restrict__ Y,
            const int* __restrict__ tgt, int H, int W, int OH, int OW,
            int tilesX, double* __restrict__ acc, int scale) {
    constexpr int NM = ONE_HOT ? 4 : 5;
    __shared__ float smem[3528 + NM * 1386];
    float* sx = smem;                  // [42][42]
    float* sy = smem + 1764;           // [42][42]
    float* tm = smem + 3528;           // [NM][42][33]
    float* red = smem;                 // aliases sx (dead after barrier 2)

    const float gk[11] = GK_INIT;

    const int bc = blockIdx.y;
    const int tile = blockIdx.x;
    const int ty = tile / tilesX, tx = tile % tilesX;
    const int oy = ty * 32, ox = tx * 32;
    const int tid = threadIdx.x;

    const float* Xb = X + (size_t)bc * H * W;
    const int b = bc / NCH, c = bc % NCH;
    const int* Tb = tgt + (size_t)b * H * W;
    const float* Yb = ONE_HOT ? (const float*)nullptr : Y + (size_t)bc * H * W;

    // ---- load halo tile (zero-pad OOB; those only feed invalid outputs)
    for (int i = tid; i < 42 * 42; i += 256) {
        int rr = i / 42, cc = i % 42;
        int gy = oy + rr, gx = ox + cc;
        bool ok = (gy < H) && (gx < W);
        float xv = ok ? Xb[(size_t)gy * W + gx] : 0.f;
        float yv;
        if (ONE_HOT) yv = (ok && Tb[(size_t)gy * W + gx] == c) ? 1.f : 0.f;
        else         yv = ok ? Yb[(size_t)gy * W + gx] : 0.f;
        sx[i] = xv; sy[i] = yv;
    }
    __syncthreads();

    // ---- horizontal conv: 42 rows x 16 col-pairs
    for (int i = tid; i < 42 * 16; i += 256) {
        int rr = i >> 4, pc = i & 15;
        const float* px = sx + rr * 42 + 2 * pc;
        const float* py = sy + rr * 42 + 2 * pc;
        float xr[12], yr[12];
#pragma unroll
        for (int t = 0; t < 6; ++t) {
            float2 vx = *(const float2*)(px + 2 * t); xr[2*t] = vx.x; xr[2*t+1] = vx.y;
            float2 vy = *(const float2*)(py + 2 * t); yr[2*t] = vy.x; yr[2*t+1] = vy.y;
        }
        float ax0 = 0, ax1 = 0, ay0 = 0, ay1 = 0;
        float axx0 = 0, axx1 = 0, axy0 = 0, axy1 = 0;
        float ayy0 = 0, ayy1 = 0;
#pragma unroll
        for (int j = 0; j < 12; ++j) {
            float xv = xr[j], yv = yr[j];
            float xx = xv * xv, xy = xv * yv;
            if (j <= 10) {
                float g = gk[j];
                ax0 += g * xv; ay0 += g * yv; axx0 += g * xx; axy0 += g * xy;
                if (!ONE_HOT) ayy0 += g * yv * yv;
            }
            if (j >= 1) {
                float g = gk[j - 1];
                ax1 += g * xv; ay1 += g * yv; axx1 += g * xx; axy1 += g * xy;
                if (!ONE_HOT) ayy1 += g * yv * yv;
            }
        }
        int o = rr * 33 + 2 * pc;
        tm[o] = ax0;               tm[o + 1] = ax1;
        tm[1386 + o] = ay0;        tm[1386 + o + 1] = ay1;
        tm[2 * 1386 + o] = axx0;   tm[2 * 1386 + o + 1] = axx1;
        tm[3 * 1386 + o] = axy0;   tm[3 * 1386 + o + 1] = axy1;
        if (!ONE_HOT) { tm[4 * 1386 + o] = ayy0; tm[4 * 1386 + o + 1] = ayy1; }
    }
    __syncthreads();

    // ---- vertical conv + SSIM: thread = (col, 4-row group)
    const float C1 = 1e-4f, C2 = 9e-4f;
    const int cc = tid & 31, rg = tid >> 5, r0 = rg * 4;
    float m1a[4] = {0, 0, 0, 0}, m2a[4] = {0, 0, 0, 0};
    float xxa[4] = {0, 0, 0, 0}, xya[4] = {0, 0, 0, 0};
    float yya[4] = {0, 0, 0, 0};
    const int vb = r0 * 33 + cc;
#pragma unroll
    for (int k = 0; k < 14; ++k) {
        float t0 = tm[vb + k * 33];
        float t1 = tm[1386 + vb + k * 33];
        float t2 = tm[2 * 1386 + vb + k * 33];
        float t3 = tm[3 * 1386 + vb + k * 33];
        float t4 = ONE_HOT ? 0.f : tm[4 * 1386 + vb + k * 33];
#pragma unroll
        for (int j = 0; j < 4; ++j) {
            int kk = k - j;
            if (kk >= 0 && kk <= 10) {
                float g = gk[kk];
                m1a[j] += g * t0; m2a[j] += g * t1;
                xxa[j] += g * t2; xya[j] += g * t3;
                if (!ONE_HOT) yya[j] += g * t4;
            }
        }
    }
    float cs_l = 0.f, ss_l = 0.f;
#pragma unroll
    for (int j = 0; j < 4; ++j) {
        if (oy + r0 + j < OH && ox + cc < OW) {
            float m1 = m1a[j], m2 = m2a[j];
            float m11 = m1 * m1, m22 = m2 * m2, m12 = m1 * m2;
            float v1 = xxa[j] - m11;
            float v2 = (ONE_HOT ? m2 : yya[j]) - m22;   // y binary: conv(y^2)=conv(y)
            float cov = xya[j] - m12;
            float cs = (2.f * cov + C2) / (v1 + v2 + C2);
            float ss = (2.f * m12 + C1) / (m11 + m22 + C1) * cs;
            cs_l += cs; ss_l += ss;
        }
    }

    // ---- block reduction
    for (int off = 32; off; off >>= 1) {
        cs_l += __shfl_down(cs_l, off);
        ss_l += __shfl_down(ss_l, off);
    }
    int wv = tid >> 6, ln = tid & 63;
    if (ln == 0) { red[wv] = cs_l; red[4 + wv] = ss_l; }
    __syncthreads();
    if (tid == 0) {
        double cs_b = (double)red[0] + (double)red[1] + (double)red[2] + (double)red[3];
        double ss_b = (double)red[4] + (double)red[5] + (double)red[6] + (double)red[7];
        atomicAdd(&acc[scale * 96 + bc], cs_b);
        atomicAdd(&acc[scale * 96 + 48 + bc], ss_b);
    }
}

// ---------------------------------------------------------------------------
__global__ void k_final(const double* __restrict__ acc, float* __restrict__ out) {
    const float wts[5] = {0.0448f, 0.2856f, 0.3001f, 0.2363f, 0.1333f};
    const float cnt[5] = {252004.f, 60516.f, 13924.f, 2916.f, 484.f}; // 502^2..22^2
    int tid = threadIdx.x;
    float msss = 0.f;
    if (tid < BC) {
        msss = 1.f;
#pragma unroll
        for (int s = 0; s < 5; ++s) {
            double a = (s < 4) ? acc[s * 96 + tid] : acc[s * 96 + 48 + tid];
            float v = fmaxf((float)(a / (double)cnt[s]), 0.f);
            msss *= powf(v, wts[s]);
        }
    }
    for (int off = 32; off; off >>= 1) msss += __shfl_down(msss, off);
    if (tid == 0) out[0] = 1.f - msss * (1.f / (float)BC);
}

// ---------------------------------------------------------------------------
extern "C" void kernel_launch(void* const* d_in, const int* in_sizes, int n_in,
                              void* d_out, int out_size, void* d_ws, size_t ws_size,
                              hipStream_t stream) {
    const float* pred = (const float*)d_in[0];
    const int*   tgt  = (const int*)d_in[1];
    float* out = (float*)d_out;

    // workspace layout
    double* acc = (double*)d_ws;                       // 480 doubles
    float* X0 = (float*)(acc + 480);                   // [48,512,512]
    float* X1 = X0 + (size_t)BC * 512 * 512;           // [48,256,256]
    float* X2 = X1 + (size_t)BC * 256 * 256;           // [48,128,128]
    float* X3 = X2 + (size_t)BC * 128 * 128;           // [48,64,64]
    float* X4 = X3 + (size_t)BC * 64 * 64;             // [48,32,32]
    float* Y1 = X4 + (size_t)BC * 32 * 32;             // [48,256,256]
    float* Y2 = Y1 + (size_t)BC * 256 * 256;
    float* Y3 = Y2 + (size_t)BC * 128 * 128;
    float* Y4 = Y3 + (size_t)BC * 64 * 64;

    k_init<<<1, 512, 0, stream>>>(acc);
    k_softmax<<<(NB * HW0 + 255) / 256, 256, 0, stream>>>(pred, X0);

    // scale 0: y = one-hot(target) on the fly
    k_ssim<true><<<dim3(16 * 16, BC), 256, 0, stream>>>(
        X0, (const float*)nullptr, tgt, 512, 512, 502, 502, 16, acc, 0);

    // pooled chains
    k_pool<<<(BC * 256 * 256 + 255) / 256, 256, 0, stream>>>(X0, X1, 512, 512);
    k_pool_y1<<<(NB * 256 * 256 + 255) / 256, 256, 0, stream>>>(tgt, Y1);

    k_ssim<false><<<dim3(8 * 8, BC), 256, 0, stream>>>(
        X1, Y1, tgt, 256, 256, 246, 246, 8, acc, 1);

    k_pool<<<(BC * 128 * 128 + 255) / 256, 256, 0, stream>>>(X1, X2, 256, 256);
    k_pool<<<(BC * 128 * 128 + 255) / 256, 256, 0, stream>>>(Y1, Y2, 256, 256);

    k_ssim<false><<<dim3(4 * 4, BC), 256, 0, stream>>>(
        X2, Y2, tgt, 128, 128, 118, 118, 4, acc, 2);

    k_pool<<<(BC * 64 * 64 + 255) / 256, 256, 0, stream>>>(X2, X3, 128, 128);
    k_pool<<<(BC * 64 * 64 + 255) / 256, 256, 0, stream>>>(Y2, Y3, 128, 128);

    k_ssim<false><<<dim3(2 * 2, BC), 256, 0, stream>>>(
        X3, Y3, tgt, 64, 64, 54, 54, 2, acc, 3);

    k_pool<<<(BC * 32 * 32 + 255) / 256, 256, 0, stream>>>(X3, X4, 64, 64);
    k_pool<<<(BC * 32 * 32 + 255) / 256, 256, 0, stream>>>(Y3, Y4, 64, 64);

    k_ssim<false><<<dim3(1, BC), 256, 0, stream>>>(
        X4, Y4, tgt, 32, 32, 22, 22, 1, acc, 4);

    k_final<<<1, 64, 0, stream>>>(acc, out);
}

// Round 3
// 315.720 us; speedup vs baseline: 1.1203x; 1.0155x over previous
//
#include <hip/hip_runtime.h>

#define NCH 12
#define NB  4
#define BC  48
#define HW0 (512 * 512)

// Gaussian 1-D weights (win=11, sigma=1.5), exact to f32 — computed offline.
#define GK_INIT { 0.00102840f, 0.00759863f, 0.03600078f, 0.10936081f, \
                  0.21300541f, 0.26601164f, 0.21300541f, 0.10936081f, \
                  0.03600078f, 0.00759863f, 0.00102840f }

// ---------------------------------------------------------------------------
__global__ void k_init(double* acc) {
    int i = threadIdx.x;
    if (i < 480) acc[i] = 0.0;   // acc[scale][2][48]
}

// softmax over the 12 channels, one thread per (b,h,w)
__global__ void k_softmax(const float* __restrict__ pred, float* __restrict__ X0) {
    int i = blockIdx.x * blockDim.x + threadIdx.x;
    if (i >= NB * HW0) return;
    int b = i >> 18;               // HW0 = 2^18
    int p = i & (HW0 - 1);
    const float* base = pred + (((size_t)b * NCH) << 18) + p;
    float v[NCH];
    float mx = -1e30f;
#pragma unroll
    for (int c = 0; c < NCH; ++c) { v[c] = base[(size_t)c << 18]; mx = fmaxf(mx, v[c]); }
    float s = 0.f;
#pragma unroll
    for (int c = 0; c < NCH; ++c) { v[c] = expf(v[c] - mx); s += v[c]; }
    float inv = 1.f / s;
    float* ob = X0 + (((size_t)b * NCH) << 18) + p;
#pragma unroll
    for (int c = 0; c < NCH; ++c) ob[(size_t)c << 18] = v[c] * inv;
}

// 2x2 avg pool, X only (float): [BC, IH, IW] -> [BC, IH/2, IW/2]
__global__ void k_pool(const float* __restrict__ in, float* __restrict__ out,
                       int IH, int IW) {
    int OH = IH >> 1, OW = IW >> 1;
    int n = BC * OH * OW;
    int i = blockIdx.x * blockDim.x + threadIdx.x;
    if (i >= n) return;
    int ow = i % OW; int t = i / OW; int oh = t % OH; int bc = t / OH;
    const float* p = in + ((size_t)bc * IH + 2 * oh) * IW + 2 * ow;
    out[i] = 0.25f * (p[0] + p[1] + p[IW] + p[IW + 1]);
}

// fused X (float) + Y (u16, value*256 exact) 2x2 pool
__global__ void k_pool2(const float* __restrict__ Xin, float* __restrict__ Xout,
                        const unsigned short* __restrict__ Yin,
                        unsigned short* __restrict__ Yout, int IH, int IW) {
    int OH = IH >> 1, OW = IW >> 1;
    int n = BC * OH * OW;
    int i = blockIdx.x * blockDim.x + threadIdx.x;
    if (i >= 2 * n) return;
    int isY = i >= n; int ii = isY ? i - n : i;
    int ow = ii % OW; int t = ii / OW; int oh = t % OH; int bc = t / OH;
    size_t base = ((size_t)bc * IH + 2 * oh) * IW + 2 * ow;
    if (isY) {
        const unsigned short* p = Yin + base;
        Yout[ii] = (unsigned short)((p[0] + p[1] + p[IW] + p[IW + 1]) >> 2);
    } else {
        const float* p = Xin + base;
        Xout[ii] = 0.25f * (p[0] + p[1] + p[IW] + p[IW + 1]);
    }
}

// Y1 (scale-1 pooled one-hot) as u16 (y*256): count-in-2x2 * 64
__global__ void k_pool_y1(const int* __restrict__ tgt, unsigned short* __restrict__ Y1) {
    int i = blockIdx.x * blockDim.x + threadIdx.x;
    if (i >= NB * 256 * 256) return;
    int w = i & 255; int t = i >> 8; int h = t & 255; int b = t >> 8;
    const int* p = tgt + ((size_t)b * 512 + 2 * h) * 512 + 2 * w;
    int t0 = p[0], t1 = p[1], t2 = p[512], t3 = p[513];
#pragma unroll
    for (int c = 0; c < NCH; ++c) {
        int cnt = (t0 == c) + (t1 == c) + (t2 == c) + (t3 == c);
        Y1[(((size_t)b * NCH + c) << 16) + (h << 8) + w] = (unsigned short)(cnt << 6);
    }
}

// ---------------------------------------------------------------------------
// Fused SSIM-index. One block = 32x32 output tile of one (b,c).
// ONE_HOT (scale 0): y stored as ballot bitmask (240 B), 4 moment arrays,
//   LDS ~29.6 KB -> 5 blocks/CU. Else: y as u16 (y*256 exact), 5 arrays,
//   ~38.5 KB -> 4 blocks/CU.
// Horizontal: 4-col groups, 14 b32 reads serve 4 outputs; sx stride 43 (odd)
//   breaks the even-bank conflict pattern. tm stride 34, float2 writes.
// Vertical: 4-row groups, 14 streamed row reads per moment, reg accumulators.
template <bool ONE_HOT>
__global__ __launch_bounds__(256, ONE_HOT ? 5 : 4)
void k_ssim(const float* __restrict__ X, const unsigned short* __restrict__ Yu,
            const int* __restrict__ tgt, int H, int W, int OH, int OW,
            int tilesX, double* __restrict__ acc, int scale) {
    constexpr int NM = ONE_HOT ? 4 : 5;
    constexpr int SS = 43;   // sx / syu row stride
    constexpr int TS = 34;   // tm row stride
    __shared__ __align__(16) float sx[42 * SS];
    __shared__ __align__(16) float tm[NM][42 * TS];
    __shared__ unsigned long long ybits[30];
    __shared__ unsigned short syu[ONE_HOT ? 2 : 42 * SS];

    const float gk[11] = GK_INIT;

    const int bc = blockIdx.y;
    const int tile = blockIdx.x;
    const int ty = tile / tilesX, tx = tile - ty * tilesX;
    const int oy = ty * 32, ox = tx * 32;
    const int tid = threadIdx.x;
    const bool interior = (oy + 41 < H) && (ox + 41 < W) &&
                          (oy + 31 < OH) && (ox + 31 < OW);

    const float* Xb = X + (size_t)bc * H * W;
    const int b = bc / NCH, cls = bc - (bc / NCH) * NCH;
    const int* Tb = tgt + (size_t)b * H * W;
    const unsigned short* Yb = ONE_HOT ? nullptr : Yu + (size_t)bc * H * W;

    // ---- halo load: 42x42, incremental (r,c), interior fast path
    {
        int r = tid / 42, c = tid - (tid / 42) * 42;
#pragma unroll
        for (int k = 0; k < 7; ++k) {
            bool inr = (k < 6) || (tid < 228);        // i = tid + 256k < 1764
            int gy = oy + r, gx = ox + c;
            bool ld = inr && (interior || (gy < H && gx < W));
            float xv = 0.f;
            bool bit = false;
            unsigned short yv = 0;
            if (ld) {
                int off = gy * W + gx;
                xv = Xb[off];
                if constexpr (ONE_HOT) bit = (Tb[off] == cls);
                else yv = Yb[off];
            }
            if constexpr (ONE_HOT) {
                unsigned long long mk = __ballot(bit);
                if ((tid & 63) == 0) ybits[(tid >> 6) + (k << 2)] = mk;
            }
            if (inr) {
                sx[r * SS + c] = xv;
                if constexpr (!ONE_HOT) syu[r * SS + c] = yv;
            }
            c += 4; r += 6;
            if (c >= 42) { c -= 42; r += 1; }
        }
        if constexpr (ONE_HOT) {
            if (tid == 0) { ybits[28] = 0ull; ybits[29] = 0ull; }
        }
    }
    __syncthreads();

    // ---- horizontal conv: 42 rows x 8 col-groups (4 outputs each)
    for (int i = tid; i < 42 * 8; i += 256) {
        int rr = i >> 3, c0 = (i & 7) << 2;
        const float* px = sx + rr * SS + c0;
        float ac[NM][4] = {};
        unsigned long long win = 0;
        if constexpr (ONE_HOT) {
            int i0 = rr * 42 + c0;
            int w = i0 >> 6, s = i0 & 63;
            unsigned long long lo = ybits[w], hi = ybits[w + 1];
            win = s ? ((lo >> s) | (hi << (64 - s))) : lo;
        }
        const unsigned short* pyu = ONE_HOT ? nullptr : syu + rr * SS + c0;
#pragma unroll
        for (int j = 0; j < 14; ++j) {
            float xv = px[j];
            float xx = xv * xv;
            float ys = 0.f, ys2 = 0.f, xys = 0.f;
            bool bit = false;
            if constexpr (ONE_HOT) bit = (win >> j) & 1;
            else { ys = (float)pyu[j]; ys2 = ys * ys; xys = xv * ys; }
#pragma unroll
            for (int o = 0; o < 4; ++o) {
                int kk = j - o;
                if (kk >= 0 && kk <= 10) {
                    float g = gk[kk];
                    ac[0][o] = fmaf(g, xv, ac[0][o]);
                    ac[2][o] = fmaf(g, xx, ac[2][o]);
                    if constexpr (ONE_HOT) {
                        float gb = bit ? g : 0.f;
                        ac[1][o] += gb;
                        ac[3][o] = fmaf(gb, xv, ac[3][o]);
                    } else {
                        ac[1][o] = fmaf(g, ys, ac[1][o]);
                        ac[3][o] = fmaf(g, xys, ac[3][o]);
                        ac[4][o] = fmaf(g, ys2, ac[4][o]);
                    }
                }
            }
        }
        int ob = rr * TS + c0;   // even -> float2 aligned
#pragma unroll
        for (int m = 0; m < NM; ++m) {
            *(float2*)&tm[m][ob]     = make_float2(ac[m][0], ac[m][1]);
            *(float2*)&tm[m][ob + 2] = make_float2(ac[m][2], ac[m][3]);
        }
    }
    __syncthreads();

    // ---- vertical conv + SSIM: thread = (col, 4-row group)
    const float C1 = 1e-4f, C2 = 9e-4f;
    const int cc = tid & 31, rg = tid >> 5, r0 = rg << 2;
    float macc[NM][4] = {};
    const int vb = r0 * TS + cc;
#pragma unroll
    for (int k = 0; k < 14; ++k) {
        float tv[NM];
#pragma unroll
        for (int m = 0; m < NM; ++m) tv[m] = tm[m][vb + k * TS];
#pragma unroll
        for (int j = 0; j < 4; ++j) {
            int kk = k - j;
            if (kk >= 0 && kk <= 10) {
                float g = gk[kk];
#pragma unroll
                for (int m = 0; m < NM; ++m) macc[m][j] = fmaf(g, tv[m], macc[m][j]);
            }
        }
    }
    float cs_l = 0.f, ss_l = 0.f;
#pragma unroll
    for (int j = 0; j < 4; ++j) {
        if (interior || (oy + r0 + j < OH && ox + cc < OW)) {
            float m1 = macc[0][j];
            float m2  = ONE_HOT ? macc[1][j] : macc[1][j] * (1.f / 256.f);
            float sxx = macc[2][j];
            float sxy_ = ONE_HOT ? macc[3][j] : macc[3][j] * (1.f / 256.f);
            float syy_ = ONE_HOT ? m2 : macc[4][j] * (1.f / 65536.f);
            float m11 = m1 * m1, m22 = m2 * m2, m12 = m1 * m2;
            float v1 = sxx - m11, v2 = syy_ - m22, cov = sxy_ - m12;
            float cs = (2.f * cov + C2) / (v1 + v2 + C2);
            float ss = (2.f * m12 + C1) / (m11 + m22 + C1) * cs;
            cs_l += cs; ss_l += ss;
        }
    }

    // ---- block reduction (red aliases sx, dead by now)
    float* red = sx;
    for (int off = 32; off; off >>= 1) {
        cs_l += __shfl_down(cs_l, off);
        ss_l += __shfl_down(ss_l, off);
    }
    int wv = tid >> 6, ln = tid & 63;
    if (ln == 0) { red[wv] = cs_l; red[4 + wv] = ss_l; }
    __syncthreads();
    if (tid == 0) {
        double cs_b = (double)red[0] + (double)red[1] + (double)red[2] + (double)red[3];
        double ss_b = (double)red[4] + (double)red[5] + (double)red[6] + (double)red[7];
        atomicAdd(&acc[scale * 96 + bc], cs_b);
        atomicAdd(&acc[scale * 96 + 48 + bc], ss_b);
    }
}

// ---------------------------------------------------------------------------
__global__ void k_final(const double* __restrict__ acc, float* __restrict__ out) {
    const float wts[5] = {0.0448f, 0.2856f, 0.3001f, 0.2363f, 0.1333f};
    const float cnt[5] = {252004.f, 60516.f, 13924.f, 2916.f, 484.f}; // 502^2..22^2
    int tid = threadIdx.x;
    float msss = 0.f;
    if (tid < BC) {
        msss = 1.f;
#pragma unroll
        for (int s = 0; s < 5; ++s) {
            double a = (s < 4) ? acc[s * 96 + tid] : acc[s * 96 + 48 + tid];
            float v = fmaxf((float)(a / (double)cnt[s]), 0.f);
            msss *= powf(v, wts[s]);
        }
    }
    for (int off = 32; off; off >>= 1) msss += __shfl_down(msss, off);
    if (tid == 0) out[0] = 1.f - msss * (1.f / (float)BC);
}

// ---------------------------------------------------------------------------
extern "C" void kernel_launch(void* const* d_in, const int* in_sizes, int n_in,
                              void* d_out, int out_size, void* d_ws, size_t ws_size,
                              hipStream_t stream) {
    const float* pred = (const float*)d_in[0];
    const int*   tgt  = (const int*)d_in[1];
    float* out = (float*)d_out;

    // workspace layout
    double* acc = (double*)d_ws;                       // 480 doubles
    float* X0 = (float*)(acc + 480);                   // [48,512,512] f32
    float* X1 = X0 + (size_t)BC * 512 * 512;
    float* X2 = X1 + (size_t)BC * 256 * 256;
    float* X3 = X2 + (size_t)BC * 128 * 128;
    float* X4 = X3 + (size_t)BC * 64 * 64;
    unsigned short* Y1 = (unsigned short*)(X4 + (size_t)BC * 32 * 32);  // u16 = y*256
    unsigned short* Y2 = Y1 + (size_t)BC * 256 * 256;
    unsigned short* Y3 = Y2 + (size_t)BC * 128 * 128;
    unsigned short* Y4 = Y3 + (size_t)BC * 64 * 64;

    k_init<<<1, 512, 0, stream>>>(acc);
    k_softmax<<<(NB * HW0 + 255) / 256, 256, 0, stream>>>(pred, X0);

    // scale 0: y = one-hot(target) on the fly (bitmask path)
    k_ssim<true><<<dim3(16 * 16, BC), 256, 0, stream>>>(
        X0, (const unsigned short*)nullptr, tgt, 512, 512, 502, 502, 16, acc, 0);

    k_pool<<<(BC * 256 * 256 + 255) / 256, 256, 0, stream>>>(X0, X1, 512, 512);
    k_pool_y1<<<(NB * 256 * 256 + 255) / 256, 256, 0, stream>>>(tgt, Y1);

    k_ssim<false><<<dim3(8 * 8, BC), 256, 0, stream>>>(
        X1, Y1, tgt, 256, 256, 246, 246, 8, acc, 1);

    k_pool2<<<(2 * BC * 128 * 128 + 255) / 256, 256, 0, stream>>>(X1, X2, Y1, Y2, 256, 256);

    k_ssim<false><<<dim3(4 * 4, BC), 256, 0, stream>>>(
        X2, Y2, tgt, 128, 128, 118, 118, 4, acc, 2);

    k_pool2<<<(2 * BC * 64 * 64 + 255) / 256, 256, 0, stream>>>(X2, X3, Y2, Y3, 128, 128);

    k_ssim<false><<<dim3(2 * 2, BC), 256, 0, stream>>>(
        X3, Y3, tgt, 64, 64, 54, 54, 2, acc, 3);

    k_pool2<<<(2 * BC * 32 * 32 + 255) / 256, 256, 0, stream>>>(X3, X4, Y3, Y4, 64, 64);

    k_ssim<false><<<dim3(1, BC), 256, 0, stream>>>(
        X4, Y4, tgt, 32, 32, 22, 22, 1, acc, 4);

    k_final<<<1, 64, 0, stream>>>(acc, out);
}

// Round 4
// 272.217 us; speedup vs baseline: 1.2993x; 1.1598x over previous
//
#include <hip/hip_runtime.h>

#define NCH 12
#define NB  4
#define BC  48
#define HW0 (512 * 512)

// Gaussian 1-D weights (win=11, sigma=1.5), exact to f32 — computed offline.
#define GK_INIT { 0.00102840f, 0.00759863f, 0.03600078f, 0.10936081f, \
                  0.21300541f, 0.26601164f, 0.21300541f, 0.10936081f, \
                  0.03600078f, 0.00759863f, 0.00102840f }

// ---------------------------------------------------------------------------
__global__ void k_init(double* acc) {
    int i = threadIdx.x;
    if (i < 480) acc[i] = 0.0;   // acc[scale][2][48]
}

// softmax over 12 channels, one thread per 4 consecutive pixels (float4)
__global__ void k_softmax(const float4* __restrict__ pred, float4* __restrict__ X0) {
    int i = blockIdx.x * blockDim.x + threadIdx.x;
    if (i >= NB * (HW0 / 4)) return;
    int b = i >> 16;                 // HW0/4 = 65536
    int p = i & 65535;
    const float4* base = pred + (((size_t)b * NCH) << 16) + p;
    float4 v[NCH];
    float4 mx = make_float4(-1e30f, -1e30f, -1e30f, -1e30f);
#pragma unroll
    for (int c = 0; c < NCH; ++c) {
        v[c] = base[(size_t)c << 16];
        mx.x = fmaxf(mx.x, v[c].x); mx.y = fmaxf(mx.y, v[c].y);
        mx.z = fmaxf(mx.z, v[c].z); mx.w = fmaxf(mx.w, v[c].w);
    }
    float4 s = make_float4(0.f, 0.f, 0.f, 0.f);
#pragma unroll
    for (int c = 0; c < NCH; ++c) {
        v[c].x = expf(v[c].x - mx.x); s.x += v[c].x;
        v[c].y = expf(v[c].y - mx.y); s.y += v[c].y;
        v[c].z = expf(v[c].z - mx.z); s.z += v[c].z;
        v[c].w = expf(v[c].w - mx.w); s.w += v[c].w;
    }
    float4 inv = make_float4(1.f / s.x, 1.f / s.y, 1.f / s.z, 1.f / s.w);
    float4* ob = X0 + (((size_t)b * NCH) << 16) + p;
#pragma unroll
    for (int c = 0; c < NCH; ++c) {
        float4 o;
        o.x = v[c].x * inv.x; o.y = v[c].y * inv.y;
        o.z = v[c].z * inv.z; o.w = v[c].w * inv.w;
        ob[(size_t)c << 16] = o;
    }
}

// ---------------------------------------------------------------------------
// Fused SSIM-index + pooled-output epilogue. One block = 32x32 output tile.
// ONE_HOT (scale 0): y from target ballot bitmask; 4 moment arrays (y^2=y).
//   LDS ~30.4 KB -> 5 blocks/CU.
// else: y as u16 (y*256 exact); 5 arrays; ~39.5 KB -> 4 blocks/CU.
// Horizontal: 8-wide col strips (42x4=168 positions, single pass), 18 reads
//   serve 8 outputs. Vertical: 4-row groups, 14 streamed reads per moment.
// POOL: emit the 2x2-pooled 16x16 X/Y tile for the next scale from LDS.
template <bool ONE_HOT, bool POOL>
__global__ __launch_bounds__(256, ONE_HOT ? 5 : 4)
void k_ssim(const float* __restrict__ X, const unsigned short* __restrict__ Yu,
            const int* __restrict__ tgt, int H, int W, int OH, int OW,
            int tilesX, double* __restrict__ acc, int scale,
            float* __restrict__ Xp, unsigned short* __restrict__ Yp) {
    constexpr int NM = ONE_HOT ? 4 : 5;
    constexpr int SS = 43;   // sx / syu row stride
    constexpr int TS = 34;   // tm row stride
    __shared__ float sx[42 * SS];
    __shared__ float tm[NM][42 * TS];
    __shared__ unsigned long long ybits[ONE_HOT ? 30 : 1];
    __shared__ unsigned short syu[ONE_HOT ? 2 : 42 * SS];
    __shared__ float red[8];

    const float gk[11] = GK_INIT;

    const int bc = blockIdx.y;
    const int tile = blockIdx.x;
    const int ty = tile / tilesX, tx = tile - ty * tilesX;
    const int oy = ty * 32, ox = tx * 32;
    const int tid = threadIdx.x;
    const bool interior = (oy + 41 < H) && (ox + 41 < W);

    const float* Xb = X + (size_t)bc * H * W;
    const int b = bc / NCH, cls = bc - (bc / NCH) * NCH;
    const int* Tb = tgt + (size_t)b * H * W;
    const unsigned short* Yb = ONE_HOT ? nullptr : Yu + (size_t)bc * H * W;

    // ---- halo load: 42x42, incremental (r,c)
    {
        int r = tid / 42, c = tid - (tid / 42) * 42;
#pragma unroll
        for (int k = 0; k < 7; ++k) {
            bool inr = (k < 6) || (tid < 228);        // i = tid + 256k < 1764
            int gy = oy + r, gx = ox + c;
            bool ld = inr && (interior || (gy < H && gx < W));
            float xv = 0.f;
            bool bit = false;
            unsigned short yv = 0;
            if (ld) {
                int off = gy * W + gx;
                xv = Xb[off];
                if constexpr (ONE_HOT) bit = (Tb[off] == cls);
                else yv = Yb[off];
            }
            if constexpr (ONE_HOT) {
                unsigned long long mk = __ballot(bit);
                if ((tid & 63) == 0) ybits[(tid >> 6) + (k << 2)] = mk;
            }
            if (inr) {
                sx[r * SS + c] = xv;
                if constexpr (!ONE_HOT) syu[r * SS + c] = yv;
            }
            c += 4; r += 6;
            if (c >= 42) { c -= 42; r += 1; }
        }
        if constexpr (ONE_HOT) {
            if (tid == 0) { ybits[28] = 0ull; ybits[29] = 0ull; }
        }
    }
    __syncthreads();

    // ---- horizontal conv: 42 rows x 4 strips of 8 outputs (168 threads)
    if (tid < 168) {
        int rr = tid >> 2, s = (tid & 3) << 3;
        const float* px = sx + rr * SS + s;
        float ac0[8] = {}, ac1[8] = {}, ac2[8] = {}, ac3[8] = {}, ac4[8] = {};
        unsigned long long win = 0;
        if constexpr (ONE_HOT) {
            int i0 = rr * 42 + s;
            int w = i0 >> 6, sh = i0 & 63;
            unsigned long long lo = ybits[w], hi = ybits[w + 1];
            win = sh ? ((lo >> sh) | (hi << (64 - sh))) : lo;
        }
        const unsigned short* pyu = ONE_HOT ? nullptr : syu + rr * SS + s;
#pragma unroll
        for (int j = 0; j < 18; ++j) {
            float xv = px[j];
            float xx = xv * xv;
            float yv, xy, yy = 0.f;
            if constexpr (ONE_HOT) {
                bool bit = (win >> j) & 1;
                yv = bit ? 1.f : 0.f;
                xy = bit ? xv : 0.f;
            } else {
                yv = (float)pyu[j];
                xy = xv * yv;
                yy = yv * yv;
            }
#pragma unroll
            for (int o = 0; o < 8; ++o) {
                int kk = j - o;
                if (kk >= 0 && kk <= 10) {
                    float g = gk[kk];
                    ac0[o] = fmaf(g, xv, ac0[o]);
                    ac1[o] = fmaf(g, yv, ac1[o]);
                    ac2[o] = fmaf(g, xx, ac2[o]);
                    ac3[o] = fmaf(g, xy, ac3[o]);
                    if constexpr (!ONE_HOT) ac4[o] = fmaf(g, yy, ac4[o]);
                }
            }
        }
        int ob = rr * TS + s;   // even -> float2 aligned
#pragma unroll
        for (int q = 0; q < 4; ++q) {
            *(float2*)&tm[0][ob + 2 * q] = make_float2(ac0[2 * q], ac0[2 * q + 1]);
            *(float2*)&tm[1][ob + 2 * q] = make_float2(ac1[2 * q], ac1[2 * q + 1]);
            *(float2*)&tm[2][ob + 2 * q] = make_float2(ac2[2 * q], ac2[2 * q + 1]);
            *(float2*)&tm[3][ob + 2 * q] = make_float2(ac3[2 * q], ac3[2 * q + 1]);
            if constexpr (!ONE_HOT)
                *(float2*)&tm[4][ob + 2 * q] = make_float2(ac4[2 * q], ac4[2 * q + 1]);
        }
    }
    __syncthreads();

    // ---- vertical conv + SSIM: thread = (col, 4-row group)
    const float C1 = 1e-4f, C2 = 9e-4f;
    const int cc = tid & 31, rg = tid >> 5, r0 = rg << 2;
    float macc[NM][4] = {};
    const int vb = r0 * TS + cc;
#pragma unroll
    for (int k = 0; k < 14; ++k) {
        float tv[NM];
#pragma unroll
        for (int m = 0; m < NM; ++m) tv[m] = tm[m][vb + k * TS];
#pragma unroll
        for (int j = 0; j < 4; ++j) {
            int kk = k - j;
            if (kk >= 0 && kk <= 10) {
                float g = gk[kk];
#pragma unroll
                for (int m = 0; m < NM; ++m) macc[m][j] = fmaf(g, tv[m], macc[m][j]);
            }
        }
    }
    float cs_l = 0.f, ss_l = 0.f;
    const bool colok = (ox + cc < OW);
#pragma unroll
    for (int j = 0; j < 4; ++j) {
        if (colok && (oy + r0 + j < OH)) {
            float m1 = macc[0][j];
            float m2  = ONE_HOT ? macc[1][j] : macc[1][j] * (1.f / 256.f);
            float sxx = macc[2][j];
            float sxy_ = ONE_HOT ? macc[3][j] : macc[3][j] * (1.f / 256.f);
            float syy_ = ONE_HOT ? m2 : macc[4][j] * (1.f / 65536.f);
            float m11 = m1 * m1, m22 = m2 * m2, m12 = m1 * m2;
            float v1 = sxx - m11, v2 = syy_ - m22, cov = sxy_ - m12;
            float d1 = m11 + m22 + C1, d2 = v1 + v2 + C2;
            float n2 = 2.f * cov + C2;
            float q = 1.f / (d1 * d2);
            cs_l = fmaf(n2 * d1, q, cs_l);
            ss_l = fmaf((2.f * m12 + C1) * n2, q, ss_l);
        }
    }

    // ---- pooled-output epilogue (reads sx/syu/ybits, stable since halo sync)
    if constexpr (POOL) {
        int py = tid >> 4, pxx = tid & 15;
        int s0 = (py * 2) * SS + pxx * 2;
        float xs = 0.25f * (sx[s0] + sx[s0 + 1] + sx[s0 + SS] + sx[s0 + SS + 1]);
        int PH = H >> 1, PW = W >> 1;
        size_t oidx = ((size_t)bc * PH + (oy >> 1) + py) * PW + (ox >> 1) + pxx;
        Xp[oidx] = xs;
        unsigned short yp;
        if constexpr (ONE_HOT) {
            int i0 = (py * 2) * 42 + pxx * 2, i1 = i0 + 42;
            unsigned c0 = (unsigned)((ybits[i0 >> 6] >> (i0 & 63)) & 1ull);
            unsigned c1 = (unsigned)((ybits[(i0 + 1) >> 6] >> ((i0 + 1) & 63)) & 1ull);
            unsigned c2 = (unsigned)((ybits[i1 >> 6] >> (i1 & 63)) & 1ull);
            unsigned c3 = (unsigned)((ybits[(i1 + 1) >> 6] >> ((i1 + 1) & 63)) & 1ull);
            yp = (unsigned short)((c0 + c1 + c2 + c3) << 6);
        } else {
            unsigned sum = (unsigned)syu[s0] + syu[s0 + 1] + syu[s0 + SS] + syu[s0 + SS + 1];
            yp = (unsigned short)(sum >> 2);
        }
        Yp[oidx] = yp;
    }

    // ---- block reduction
    for (int off = 32; off; off >>= 1) {
        cs_l += __shfl_down(cs_l, off);
        ss_l += __shfl_down(ss_l, off);
    }
    int wv = tid >> 6, ln = tid & 63;
    if (ln == 0) { red[wv] = cs_l; red[4 + wv] = ss_l; }
    __syncthreads();
    if (tid == 0) {
        double cs_b = (double)red[0] + (double)red[1] + (double)red[2] + (double)red[3];
        double ss_b = (double)red[4] + (double)red[5] + (double)red[6] + (double)red[7];
        atomicAdd(&acc[scale * 96 + bc], cs_b);
        atomicAdd(&acc[scale * 96 + 48 + bc], ss_b);
    }
}

// ---------------------------------------------------------------------------
__global__ void k_final(const double* __restrict__ acc, float* __restrict__ out) {
    const float wts[5] = {0.0448f, 0.2856f, 0.3001f, 0.2363f, 0.1333f};
    const float cnt[5] = {252004.f, 60516.f, 13924.f, 2916.f, 484.f}; // 502^2..22^2
    int tid = threadIdx.x;
    float msss = 0.f;
    if (tid < BC) {
        msss = 1.f;
#pragma unroll
        for (int s = 0; s < 5; ++s) {
            double a = (s < 4) ? acc[s * 96 + tid] : acc[s * 96 + 48 + tid];
            float v = fmaxf((float)(a / (double)cnt[s]), 0.f);
            msss *= powf(v, wts[s]);
        }
    }
    for (int off = 32; off; off >>= 1) msss += __shfl_down(msss, off);
    if (tid == 0) out[0] = 1.f - msss * (1.f / (float)BC);
}

// ---------------------------------------------------------------------------
extern "C" void kernel_launch(void* const* d_in, const int* in_sizes, int n_in,
                              void* d_out, int out_size, void* d_ws, size_t ws_size,
                              hipStream_t stream) {
    const float* pred = (const float*)d_in[0];
    const int*   tgt  = (const int*)d_in[1];
    float* out = (float*)d_out;

    // workspace layout
    double* acc = (double*)d_ws;                       // 480 doubles
    float* X0 = (float*)(acc + 480);                   // [48,512,512] f32
    float* X1 = X0 + (size_t)BC * 512 * 512;
    float* X2 = X1 + (size_t)BC * 256 * 256;
    float* X3 = X2 + (size_t)BC * 128 * 128;
    float* X4 = X3 + (size_t)BC * 64 * 64;
    unsigned short* Y1 = (unsigned short*)(X4 + (size_t)BC * 32 * 32);  // u16 = y*256
    unsigned short* Y2 = Y1 + (size_t)BC * 256 * 256;
    unsigned short* Y3 = Y2 + (size_t)BC * 128 * 128;
    unsigned short* Y4 = Y3 + (size_t)BC * 64 * 64;

    k_init<<<1, 512, 0, stream>>>(acc);
    k_softmax<<<(NB * (HW0 / 4) + 255) / 256, 256, 0, stream>>>(
        (const float4*)pred, (float4*)X0);

    // scale 0: y = one-hot(target) on the fly; pools X1/Y1 in epilogue
    k_ssim<true, true><<<dim3(16 * 16, BC), 256, 0, stream>>>(
        X0, (const unsigned short*)nullptr, tgt, 512, 512, 502, 502, 16,
        acc, 0, X1, Y1);

    k_ssim<false, true><<<dim3(8 * 8, BC), 256, 0, stream>>>(
        X1, Y1, tgt, 256, 256, 246, 246, 8, acc, 1, X2, Y2);

    k_ssim<false, true><<<dim3(4 * 4, BC), 256, 0, stream>>>(
        X2, Y2, tgt, 128, 128, 118, 118, 4, acc, 2, X3, Y3);

    k_ssim<false, true><<<dim3(2 * 2, BC), 256, 0, stream>>>(
        X3, Y3, tgt, 64, 64, 54, 54, 2, acc, 3, X4, Y4);

    k_ssim<false, false><<<dim3(1, BC), 256, 0, stream>>>(
        X4, Y4, tgt, 32, 32, 22, 22, 1, acc, 4, nullptr, nullptr);

    k_final<<<1, 64, 0, stream>>>(acc, out);
}

// Round 5
// 265.769 us; speedup vs baseline: 1.3308x; 1.0243x over previous
//
#include <hip/hip_runtime.h>

#define NCH 12
#define NB  4
#define BC  48
#define HW0 (512 * 512)

// Gaussian 1-D weights (win=11, sigma=1.5), exact to f32 — computed offline.
#define GK_INIT { 0.00102840f, 0.00759863f, 0.03600078f, 0.10936081f, \
                  0.21300541f, 0.26601164f, 0.21300541f, 0.10936081f, \
                  0.03600078f, 0.00759863f, 0.00102840f }

// ---------------------------------------------------------------------------
// softmax over 12 channels, one thread per 4 consecutive pixels (float4).
// Block 0 also zero-inits the accumulator array (saves a launch).
__global__ void k_softmax(const float4* __restrict__ pred, float4* __restrict__ X0,
                          double* __restrict__ acc) {
    if (blockIdx.x == 0) {
        for (int t = threadIdx.x; t < 480; t += 256) acc[t] = 0.0;
    }
    int i = blockIdx.x * blockDim.x + threadIdx.x;
    if (i >= NB * (HW0 / 4)) return;
    int b = i >> 16;                 // HW0/4 = 65536
    int p = i & 65535;
    const float4* base = pred + (((size_t)b * NCH) << 16) + p;
    float4 v[NCH];
    float4 mx = make_float4(-1e30f, -1e30f, -1e30f, -1e30f);
#pragma unroll
    for (int c = 0; c < NCH; ++c) {
        v[c] = base[(size_t)c << 16];
        mx.x = fmaxf(mx.x, v[c].x); mx.y = fmaxf(mx.y, v[c].y);
        mx.z = fmaxf(mx.z, v[c].z); mx.w = fmaxf(mx.w, v[c].w);
    }
    float4 s = make_float4(0.f, 0.f, 0.f, 0.f);
#pragma unroll
    for (int c = 0; c < NCH; ++c) {
        v[c].x = expf(v[c].x - mx.x); s.x += v[c].x;
        v[c].y = expf(v[c].y - mx.y); s.y += v[c].y;
        v[c].z = expf(v[c].z - mx.z); s.z += v[c].z;
        v[c].w = expf(v[c].w - mx.w); s.w += v[c].w;
    }
    float4 inv = make_float4(1.f / s.x, 1.f / s.y, 1.f / s.z, 1.f / s.w);
    float4* ob = X0 + (((size_t)b * NCH) << 16) + p;
#pragma unroll
    for (int c = 0; c < NCH; ++c) {
        float4 o;
        o.x = v[c].x * inv.x; o.y = v[c].y * inv.y;
        o.z = v[c].z * inv.z; o.w = v[c].w * inv.w;
        ob[(size_t)c << 16] = o;
    }
}

// ---------------------------------------------------------------------------
// Fused SSIM-index + pooled-output epilogue. One block = 32x32 output tile.
// ONE_HOT (scale 0): y from target ballot bitmask; moments y^2==y.
// Moments 0-3 (m1,m2,xx,xy) interleaved as float4 in LDS (tm4, stride 34):
//   vertical pass does 14 ds_read_b128 instead of 56 ds_read_b32.
// Horizontal: 6-wide col strips -> 42x6=252 of 256 threads active, 1 pass.
// POOL: emit the 2x2-pooled 16x16 X/Y tile for the next scale from LDS.
template <bool ONE_HOT, bool POOL>
__global__ __launch_bounds__(256, ONE_HOT ? 5 : 4)
void k_ssim(const float* __restrict__ X, const unsigned short* __restrict__ Yu,
            const int* __restrict__ tgt, int H, int W, int OH, int OW,
            int tilesX, double* __restrict__ acc, int scale,
            float* __restrict__ Xp, unsigned short* __restrict__ Yp) {
    constexpr int SS = 43;   // sx / syu row stride (floats)
    constexpr int TS = 34;   // tm4 row stride (float4s); cols 32-35 = pad
    __shared__ float sx[42 * SS + 4];
    __shared__ float4 tm4[42 * TS];
    __shared__ float tm5[ONE_HOT ? 4 : 42 * TS];      // yy moment (non-onehot)
    __shared__ unsigned long long ybits[30];
    __shared__ unsigned short syu[ONE_HOT ? 2 : 42 * SS + 4];
    __shared__ float red[8];

    const float gk[11] = GK_INIT;

    const int bc = blockIdx.y;
    const int tile = blockIdx.x;
    const int ty = tile / tilesX, tx = tile - ty * tilesX;
    const int oy = ty * 32, ox = tx * 32;
    const int tid = threadIdx.x;
    const bool interior = (oy + 41 < H) && (ox + 41 < W);

    const float* Xb = X + (size_t)bc * H * W;
    const int b = bc / NCH, cls = bc - (bc / NCH) * NCH;
    const int* Tb = tgt + (size_t)b * H * W;
    const unsigned short* Yb = ONE_HOT ? nullptr : Yu + (size_t)bc * H * W;

    // ---- halo load: 42x42, incremental (r,c)
    {
        int r = tid / 42, c = tid - (tid / 42) * 42;
#pragma unroll
        for (int k = 0; k < 7; ++k) {
            bool inr = (k < 6) || (tid < 228);        // i = tid + 256k < 1764
            int gy = oy + r, gx = ox + c;
            bool ld = inr && (interior || (gy < H && gx < W));
            float xv = 0.f;
            bool bit = false;
            unsigned short yv = 0;
            if (ld) {
                int off = gy * W + gx;
                xv = Xb[off];
                if constexpr (ONE_HOT) bit = (Tb[off] == cls);
                else yv = Yb[off];
            }
            if constexpr (ONE_HOT) {
                unsigned long long mk = __ballot(bit);
                if ((tid & 63) == 0) ybits[(tid >> 6) + (k << 2)] = mk;
            }
            if (inr) {
                sx[r * SS + c] = xv;
                if constexpr (!ONE_HOT) syu[r * SS + c] = yv;
            }
            c += 4; r += 6;
            if (c >= 42) { c -= 42; r += 1; }
        }
        if constexpr (ONE_HOT) {
            if (tid == 0) { ybits[28] = 0ull; ybits[29] = 0ull; }
        }
    }
    __syncthreads();

    // ---- horizontal conv: 42 rows x 6 strips of 6 outputs (252 threads)
    if (tid < 252) {
        int rr = tid / 6, s = tid - (tid / 6) * 6;
        int c0 = s * 6;
        const float* px = sx + rr * SS + c0;
        float ac0[6] = {}, ac1[6] = {}, ac2[6] = {}, ac3[6] = {}, ac4[6] = {};
        unsigned long long win = 0;
        if constexpr (ONE_HOT) {
            int i0 = rr * 42 + c0;
            int w = i0 >> 6, sh = i0 & 63;
            unsigned long long lo = ybits[w], hi = ybits[w + 1];
            win = sh ? ((lo >> sh) | (hi << (64 - sh))) : lo;
        }
        const unsigned short* pyu = ONE_HOT ? nullptr : syu + rr * SS + c0;
#pragma unroll
        for (int j = 0; j < 16; ++j) {
            float xv = px[j];
            float xx = xv * xv;
            float yv, xy, yy = 0.f;
            if constexpr (ONE_HOT) {
                bool bit = (win >> j) & 1;
                yv = bit ? 1.f : 0.f;
                xy = bit ? xv : 0.f;
            } else {
                yv = (float)pyu[j];
                xy = xv * yv;
                yy = yv * yv;
            }
#pragma unroll
            for (int o = 0; o < 6; ++o) {
                int kk = j - o;
                if (kk >= 0 && kk <= 10) {
                    float g = gk[kk];
                    ac0[o] = fmaf(g, xv, ac0[o]);
                    ac1[o] = fmaf(g, yv, ac1[o]);
                    ac2[o] = fmaf(g, xx, ac2[o]);
                    ac3[o] = fmaf(g, xy, ac3[o]);
                    if constexpr (!ONE_HOT) ac4[o] = fmaf(g, yy, ac4[o]);
                }
            }
        }
        int ob = rr * TS + c0;
#pragma unroll
        for (int o = 0; o < 6; ++o) {
            if (c0 + o < 32) {       // s==5 strip covers only cols 30,31
                tm4[ob + o] = make_float4(ac0[o], ac1[o], ac2[o], ac3[o]);
                if constexpr (!ONE_HOT) tm5[ob + o] = ac4[o];
            }
        }
    }
    __syncthreads();

    // ---- vertical conv + SSIM: thread = (col, 4-row group)
    const float C1 = 1e-4f, C2 = 9e-4f;
    const int cc = tid & 31, rg = tid >> 5, r0 = rg << 2;
    float a0[4] = {}, a1[4] = {}, a2[4] = {}, a3[4] = {}, a4[4] = {};
    const int vb = r0 * TS + cc;
#pragma unroll
    for (int k = 0; k < 14; ++k) {
        float4 tv = tm4[vb + k * TS];
        float t4 = ONE_HOT ? 0.f : tm5[vb + k * TS];
#pragma unroll
        for (int j = 0; j < 4; ++j) {
            int kk = k - j;
            if (kk >= 0 && kk <= 10) {
                float g = gk[kk];
                a0[j] = fmaf(g, tv.x, a0[j]);
                a1[j] = fmaf(g, tv.y, a1[j]);
                a2[j] = fmaf(g, tv.z, a2[j]);
                a3[j] = fmaf(g, tv.w, a3[j]);
                if constexpr (!ONE_HOT) a4[j] = fmaf(g, t4, a4[j]);
            }
        }
    }
    float cs_l = 0.f, ss_l = 0.f;
    const bool colok = (ox + cc < OW);
#pragma unroll
    for (int j = 0; j < 4; ++j) {
        if (colok && (oy + r0 + j < OH)) {
            float m1 = a0[j];
            float m2  = ONE_HOT ? a1[j] : a1[j] * (1.f / 256.f);
            float sxx = a2[j];
            float sxy_ = ONE_HOT ? a3[j] : a3[j] * (1.f / 256.f);
            float syy_ = ONE_HOT ? m2 : a4[j] * (1.f / 65536.f);
            float m11 = m1 * m1, m22 = m2 * m2, m12 = m1 * m2;
            float v1 = sxx - m11, v2 = syy_ - m22, cov = sxy_ - m12;
            float d1 = m11 + m22 + C1, d2 = v1 + v2 + C2;
            float n2 = 2.f * cov + C2;
            float q = 1.f / (d1 * d2);
            cs_l = fmaf(n2 * d1, q, cs_l);
            ss_l = fmaf((2.f * m12 + C1) * n2, q, ss_l);
        }
    }

    // ---- pooled-output epilogue (reads sx/syu/ybits, stable since halo sync)
    if constexpr (POOL) {
        int py = tid >> 4, pxx = tid & 15;
        int s0 = (py * 2) * SS + pxx * 2;
        float xs = 0.25f * (sx[s0] + sx[s0 + 1] + sx[s0 + SS] + sx[s0 + SS + 1]);
        int PH = H >> 1, PW = W >> 1;
        size_t oidx = ((size_t)bc * PH + (oy >> 1) + py) * PW + (ox >> 1) + pxx;
        Xp[oidx] = xs;
        unsigned short yp;
        if constexpr (ONE_HOT) {
            int i0 = (py * 2) * 42 + pxx * 2, i1 = i0 + 42;
            unsigned c0 = (unsigned)((ybits[i0 >> 6] >> (i0 & 63)) & 1ull);
            unsigned c1 = (unsigned)((ybits[(i0 + 1) >> 6] >> ((i0 + 1) & 63)) & 1ull);
            unsigned c2 = (unsigned)((ybits[i1 >> 6] >> (i1 & 63)) & 1ull);
            unsigned c3 = (unsigned)((ybits[(i1 + 1) >> 6] >> ((i1 + 1) & 63)) & 1ull);
            yp = (unsigned short)((c0 + c1 + c2 + c3) << 6);
        } else {
            unsigned sum = (unsigned)syu[s0] + syu[s0 + 1] + syu[s0 + SS] + syu[s0 + SS + 1];
            yp = (unsigned short)(sum >> 2);
        }
        Yp[oidx] = yp;
    }

    // ---- block reduction
    for (int off = 32; off; off >>= 1) {
        cs_l += __shfl_down(cs_l, off);
        ss_l += __shfl_down(ss_l, off);
    }
    int wv = tid >> 6, ln = tid & 63;
    if (ln == 0) { red[wv] = cs_l; red[4 + wv] = ss_l; }
    __syncthreads();
    if (tid == 0) {
        double cs_b = (double)red[0] + (double)red[1] + (double)red[2] + (double)red[3];
        double ss_b = (double)red[4] + (double)red[5] + (double)red[6] + (double)red[7];
        atomicAdd(&acc[scale * 96 + bc], cs_b);
        atomicAdd(&acc[scale * 96 + 48 + bc], ss_b);
    }
}

// ---------------------------------------------------------------------------
__global__ void k_final(const double* __restrict__ acc, float* __restrict__ out) {
    const float wts[5] = {0.0448f, 0.2856f, 0.3001f, 0.2363f, 0.1333f};
    const float cnt[5] = {252004.f, 60516.f, 13924.f, 2916.f, 484.f}; // 502^2..22^2
    int tid = threadIdx.x;
    float msss = 0.f;
    if (tid < BC) {
        msss = 1.f;
#pragma unroll
        for (int s = 0; s < 5; ++s) {
            double a = (s < 4) ? acc[s * 96 + tid] : acc[s * 96 + 48 + tid];
            float v = fmaxf((float)(a / (double)cnt[s]), 0.f);
            msss *= powf(v, wts[s]);
        }
    }
    for (int off = 32; off; off >>= 1) msss += __shfl_down(msss, off);
    if (tid == 0) out[0] = 1.f - msss * (1.f / (float)BC);
}

// ---------------------------------------------------------------------------
extern "C" void kernel_launch(void* const* d_in, const int* in_sizes, int n_in,
                              void* d_out, int out_size, void* d_ws, size_t ws_size,
                              hipStream_t stream) {
    const float* pred = (const float*)d_in[0];
    const int*   tgt  = (const int*)d_in[1];
    float* out = (float*)d_out;

    // workspace layout
    double* acc = (double*)d_ws;                       // 480 doubles
    float* X0 = (float*)(acc + 480);                   // [48,512,512] f32
    float* X1 = X0 + (size_t)BC * 512 * 512;
    float* X2 = X1 + (size_t)BC * 256 * 256;
    float* X3 = X2 + (size_t)BC * 128 * 128;
    float* X4 = X3 + (size_t)BC * 64 * 64;
    unsigned short* Y1 = (unsigned short*)(X4 + (size_t)BC * 32 * 32);  // u16 = y*256
    unsigned short* Y2 = Y1 + (size_t)BC * 256 * 256;
    unsigned short* Y3 = Y2 + (size_t)BC * 128 * 128;
    unsigned short* Y4 = Y3 + (size_t)BC * 64 * 64;

    k_softmax<<<(NB * (HW0 / 4) + 255) / 256, 256, 0, stream>>>(
        (const float4*)pred, (float4*)X0, acc);

    // scale 0: y = one-hot(target) on the fly; pools X1/Y1 in epilogue
    k_ssim<true, true><<<dim3(16 * 16, BC), 256, 0, stream>>>(
        X0, (const unsigned short*)nullptr, tgt, 512, 512, 502, 502, 16,
        acc, 0, X1, Y1);

    k_ssim<false, true><<<dim3(8 * 8, BC), 256, 0, stream>>>(
        X1, Y1, tgt, 256, 256, 246, 246, 8, acc, 1, X2, Y2);

    k_ssim<false, true><<<dim3(4 * 4, BC), 256, 0, stream>>>(
        X2, Y2, tgt, 128, 128, 118, 118, 4, acc, 2, X3, Y3);

    k_ssim<false, true><<<dim3(2 * 2, BC), 256, 0, stream>>>(
        X3, Y3, tgt, 64, 64, 54, 54, 2, acc, 3, X4, Y4);

    k_ssim<false, false><<<dim3(1, BC), 256, 0, stream>>>(
        X4, Y4, tgt, 32, 32, 22, 22, 1, acc, 4, nullptr, nullptr);

    k_final<<<1, 64, 0, stream>>>(acc, out);
}